// Round 1
// baseline (15517.007 us; speedup 1.0000x reference)
//
#include <hip/hip_runtime.h>
#include <hip/hip_bf16.h>

typedef float f32x4 __attribute__((ext_vector_type(4)));
typedef __bf16 bf16x8 __attribute__((ext_vector_type(8)));

__device__ __forceinline__ unsigned short f2bf(float f) {
    unsigned int u = __builtin_bit_cast(unsigned int, f);
    u += 0x7fffu + ((u >> 16) & 1u);
    return (unsigned short)(u >> 16);
}

// ---------------------------------------------------------------------------
// GEMM: C[M,N] = A[M,K] @ W[N,K]^T + bias[N]  (optional ReLU)
// A, W fp32 in global; converted to bf16 during LDS staging; MFMA 16x16x32.
// Block: 256 threads (4 waves), tile 128x128, BK=64.
// ---------------------------------------------------------------------------
__global__ __launch_bounds__(256) void gemm_kernel(
    const float* __restrict__ A, const float* __restrict__ W,
    const float* __restrict__ bias, float* __restrict__ C,
    int N, int K, int relu)
{
    __shared__ alignas(16) unsigned short As[128][72];
    __shared__ alignas(16) unsigned short Bs[128][72];

    const int tid  = threadIdx.x;
    const int bn   = blockIdx.x, bm = blockIdx.y;
    const int wave = tid >> 6, lane = tid & 63;
    const int wm   = (wave >> 1) * 64, wn = (wave & 1) * 64;
    const int l15  = lane & 15, quad = lane >> 4;

    f32x4 acc[4][4];
#pragma unroll
    for (int i = 0; i < 4; i++)
#pragma unroll
        for (int j = 0; j < 4; j++) acc[i][j] = f32x4{0.f, 0.f, 0.f, 0.f};

    for (int k0 = 0; k0 < K; k0 += 64) {
        __syncthreads();
#pragma unroll
        for (int i = 0; i < 8; i++) {
            int idx = tid + i * 256;           // 0..2047
            int row = idx >> 4;                // 0..127
            int c4  = (idx & 15) << 2;         // 0..60
            float4 av = *(const float4*)&A[(size_t)(bm * 128 + row) * K + k0 + c4];
            ushort4 ua;
            ua.x = f2bf(av.x); ua.y = f2bf(av.y); ua.z = f2bf(av.z); ua.w = f2bf(av.w);
            *(ushort4*)&As[row][c4] = ua;
            float4 wv = *(const float4*)&W[(size_t)(bn * 128 + row) * K + k0 + c4];
            ushort4 ub;
            ub.x = f2bf(wv.x); ub.y = f2bf(wv.y); ub.z = f2bf(wv.z); ub.w = f2bf(wv.w);
            *(ushort4*)&Bs[row][c4] = ub;
        }
        __syncthreads();

#pragma unroll
        for (int ks = 0; ks < 2; ks++) {
            bf16x8 a[4], b[4];
#pragma unroll
            for (int mt = 0; mt < 4; mt++)
                a[mt] = *reinterpret_cast<const bf16x8*>(&As[wm + mt * 16 + l15][ks * 32 + quad * 8]);
#pragma unroll
            for (int nt = 0; nt < 4; nt++)
                b[nt] = *reinterpret_cast<const bf16x8*>(&Bs[wn + nt * 16 + l15][ks * 32 + quad * 8]);
#pragma unroll
            for (int mt = 0; mt < 4; mt++)
#pragma unroll
                for (int nt = 0; nt < 4; nt++)
                    acc[mt][nt] = __builtin_amdgcn_mfma_f32_16x16x32_bf16(
                        a[mt], b[nt], acc[mt][nt], 0, 0, 0);
        }
    }

#pragma unroll
    for (int nt = 0; nt < 4; nt++) {
        int gn = bn * 128 + wn + nt * 16 + l15;
        float bv = bias[gn];
#pragma unroll
        for (int mt = 0; mt < 4; mt++) {
            int gm0 = bm * 128 + wm + mt * 16 + quad * 4;
#pragma unroll
            for (int r = 0; r < 4; r++) {
                float v = acc[mt][nt][r] + bv;
                if (relu) v = fmaxf(v, 0.f);
                C[(size_t)(gm0 + r) * N + gn] = v;
            }
        }
    }
}

// ---------------------------------------------------------------------------
// Flash attention, causal. One block = (b, h, 64-row q tile). 256 threads.
// qkv: [B*S, 3*1024] fp32.  ctx out: [B*S, 1024] fp32.
// ---------------------------------------------------------------------------
__global__ __launch_bounds__(256) void attn_kernel(
    const float* __restrict__ qkv, float* __restrict__ ctx)
{
    const int qt = blockIdx.x;          // 0..15
    const int bh = blockIdx.y;          // 0..63
    const int b  = bh >> 4, h = bh & 15;
    const int tid = threadIdx.x, wave = tid >> 6, lane = tid & 63;
    const int l15 = lane & 15, quad = lane >> 4;
    const float scale = 0.125f;         // 1/sqrt(64)

    __shared__ alignas(16) unsigned short Qs[64][72];
    __shared__ alignas(16) unsigned short Ks[64][72];
    __shared__ alignas(16) unsigned short Vt[64][72];  // transposed: [d][k]
    __shared__ alignas(16) unsigned short Ps[64][72];  // per-wave 16-row strips

    // stage Q tile (64 q rows x 64 dh), bf16
    {
        const float* qbase = qkv + (size_t)(b * 1024 + qt * 64) * 3072 + h * 64;
#pragma unroll
        for (int i = 0; i < 4; i++) {
            int idx = tid + i * 256;
            int row = idx >> 4, c4 = (idx & 15) << 2;
            float4 v = *(const float4*)&qbase[(size_t)row * 3072 + c4];
            ushort4 u;
            u.x = f2bf(v.x); u.y = f2bf(v.y); u.z = f2bf(v.z); u.w = f2bf(v.w);
            *(ushort4*)&Qs[row][c4] = u;
        }
    }

    f32x4 O[4];
#pragma unroll
    for (int dt = 0; dt < 4; dt++) O[dt] = f32x4{0.f, 0.f, 0.f, 0.f};
    float m_run[4], l_run[4];
#pragma unroll
    for (int r = 0; r < 4; r++) { m_run[r] = -__builtin_inff(); l_run[r] = 0.f; }

    const int q_row_base = qt * 64 + wave * 16;

    for (int j = 0; j <= qt; j++) {
        __syncthreads();
        const float* kbase = qkv + (size_t)(b * 1024 + j * 64) * 3072 + 1024 + h * 64;
        const float* vbase = qkv + (size_t)(b * 1024 + j * 64) * 3072 + 2048 + h * 64;
#pragma unroll
        for (int i = 0; i < 4; i++) {
            int idx = tid + i * 256;
            int row = idx >> 4, c4 = (idx & 15) << 2;
            float4 kv = *(const float4*)&kbase[(size_t)row * 3072 + c4];
            ushort4 u;
            u.x = f2bf(kv.x); u.y = f2bf(kv.y); u.z = f2bf(kv.z); u.w = f2bf(kv.w);
            *(ushort4*)&Ks[row][c4] = u;
            float4 vv = *(const float4*)&vbase[(size_t)row * 3072 + c4];
            Vt[c4 + 0][row] = f2bf(vv.x);
            Vt[c4 + 1][row] = f2bf(vv.y);
            Vt[c4 + 2][row] = f2bf(vv.z);
            Vt[c4 + 3][row] = f2bf(vv.w);
        }
        __syncthreads();

        // S = Q K^T (16 q rows per wave x 64 k cols)
        f32x4 Sc[4];
#pragma unroll
        for (int nt = 0; nt < 4; nt++) Sc[nt] = f32x4{0.f, 0.f, 0.f, 0.f};
#pragma unroll
        for (int ks = 0; ks < 2; ks++) {
            bf16x8 aq = *reinterpret_cast<const bf16x8*>(&Qs[wave * 16 + l15][ks * 32 + quad * 8]);
#pragma unroll
            for (int nt = 0; nt < 4; nt++) {
                bf16x8 bk = *reinterpret_cast<const bf16x8*>(&Ks[nt * 16 + l15][ks * 32 + quad * 8]);
                Sc[nt] = __builtin_amdgcn_mfma_f32_16x16x32_bf16(aq, bk, Sc[nt], 0, 0, 0);
            }
        }

        // scale + causal mask + running max
        float alpha[4];
#pragma unroll
        for (int r = 0; r < 4; r++) {
            int qg = q_row_base + quad * 4 + r;
            float mx = -__builtin_inff();
#pragma unroll
            for (int nt = 0; nt < 4; nt++) {
                int kg = j * 64 + nt * 16 + l15;
                float s = Sc[nt][r] * scale;
                if (kg > qg) s = -__builtin_inff();
                Sc[nt][r] = s;
                mx = fmaxf(mx, s);
            }
#pragma unroll
            for (int off = 1; off < 16; off <<= 1) mx = fmaxf(mx, __shfl_xor(mx, off));
            float mnew = fmaxf(m_run[r], mx);
            alpha[r] = __expf(m_run[r] - mnew);
            m_run[r] = mnew;
        }

        // p = exp(s - m), row sums, update l
#pragma unroll
        for (int r = 0; r < 4; r++) {
            float sum = 0.f;
#pragma unroll
            for (int nt = 0; nt < 4; nt++) {
                float p = __expf(Sc[nt][r] - m_run[r]);
                Sc[nt][r] = p;
                sum += p;
            }
#pragma unroll
            for (int off = 1; off < 16; off <<= 1) sum += __shfl_xor(sum, off);
            l_run[r] = l_run[r] * alpha[r] + sum;
        }

        // rescale O by alpha
#pragma unroll
        for (int dt = 0; dt < 4; dt++)
#pragma unroll
            for (int r = 0; r < 4; r++) O[dt][r] *= alpha[r];

        // P (C-layout) -> LDS -> A-layout frags
#pragma unroll
        for (int nt = 0; nt < 4; nt++)
#pragma unroll
            for (int r = 0; r < 4; r++)
                Ps[wave * 16 + quad * 4 + r][nt * 16 + l15] = f2bf(Sc[nt][r]);

        // O += P @ V   (per-wave Ps strip; same-wave DS ordering is in-order)
#pragma unroll
        for (int ks = 0; ks < 2; ks++) {
            bf16x8 ap = *reinterpret_cast<const bf16x8*>(&Ps[wave * 16 + l15][ks * 32 + quad * 8]);
#pragma unroll
            for (int dt = 0; dt < 4; dt++) {
                bf16x8 bv = *reinterpret_cast<const bf16x8*>(&Vt[dt * 16 + l15][ks * 32 + quad * 8]);
                O[dt] = __builtin_amdgcn_mfma_f32_16x16x32_bf16(ap, bv, O[dt], 0, 0, 0);
            }
        }
    }

    // epilogue: ctx[b, q, h*64 + d] = O / l
    float* obase = ctx + (size_t)(b * 1024 + qt * 64 + wave * 16) * 1024 + h * 64;
#pragma unroll
    for (int r = 0; r < 4; r++) {
        float inv = 1.f / l_run[r];
#pragma unroll
        for (int dt = 0; dt < 4; dt++)
            obase[(size_t)(quad * 4 + r) * 1024 + dt * 16 + l15] = O[dt][r] * inv;
    }
}

// ---------------------------------------------------------------------------
// h = LayerNorm(h + r) * w + b   (row = 1024 floats; one block per row)
// ---------------------------------------------------------------------------
__global__ __launch_bounds__(256) void ln_residual_kernel(
    float* __restrict__ h, const float* __restrict__ r,
    const float* __restrict__ w, const float* __restrict__ b)
{
    const int row = blockIdx.x;
    const int tid = threadIdx.x;
    const int lane = tid & 63, wave = tid >> 6;

    float4 hv = *(float4*)&h[(size_t)row * 1024 + tid * 4];
    float4 rv = *(const float4*)&r[(size_t)row * 1024 + tid * 4];
    float x0 = hv.x + rv.x, x1 = hv.y + rv.y, x2 = hv.z + rv.z, x3 = hv.w + rv.w;

    float s  = x0 + x1 + x2 + x3;
    float s2 = x0 * x0 + x1 * x1 + x2 * x2 + x3 * x3;
#pragma unroll
    for (int off = 32; off >= 1; off >>= 1) {
        s  += __shfl_xor(s, off);
        s2 += __shfl_xor(s2, off);
    }
    __shared__ float ls[4], ls2[4];
    if (lane == 0) { ls[wave] = s; ls2[wave] = s2; }
    __syncthreads();
    s  = ls[0] + ls[1] + ls[2] + ls[3];
    s2 = ls2[0] + ls2[1] + ls2[2] + ls2[3];

    const float inv_n = 1.f / 1024.f;
    float mean = s * inv_n;
    float var  = s2 * inv_n - mean * mean;
    float rstd = rsqrtf(var + 1e-5f);

    float4 wv = *(const float4*)&w[tid * 4];
    float4 bv = *(const float4*)&b[tid * 4];
    float4 out;
    out.x = (x0 - mean) * rstd * wv.x + bv.x;
    out.y = (x1 - mean) * rstd * wv.y + bv.y;
    out.z = (x2 - mean) * rstd * wv.z + bv.z;
    out.w = (x3 - mean) * rstd * wv.w + bv.w;
    *(float4*)&h[(size_t)row * 1024 + tid * 4] = out;
}

__global__ __launch_bounds__(256) void copy_kernel(
    const float* __restrict__ in, float* __restrict__ out)
{
    int i = blockIdx.x * 256 + threadIdx.x;
    ((float4*)out)[i] = ((const float4*)in)[i];
}

// ---------------------------------------------------------------------------
extern "C" void kernel_launch(void* const* d_in, const int* in_sizes, int n_in,
                              void* d_out, int out_size, void* d_ws, size_t ws_size,
                              hipStream_t stream)
{
    const float* x     = (const float*)d_in[0];
    const float* qkv_w = (const float*)d_in[1];
    const float* qkv_b = (const float*)d_in[2];
    const float* out_w = (const float*)d_in[3];
    const float* out_b = (const float*)d_in[4];
    const float* w1    = (const float*)d_in[5];
    const float* b1    = (const float*)d_in[6];
    const float* w2    = (const float*)d_in[7];
    const float* b2    = (const float*)d_in[8];
    const float* ln1w  = (const float*)d_in[9];
    const float* ln1b  = (const float*)d_in[10];
    const float* ln2w  = (const float*)d_in[11];
    const float* ln2b  = (const float*)d_in[12];

    float* h = (float*)d_out;                       // residual stream [4096,1024]
    float* ws = (float*)d_ws;
    // shared region: qkv [4096,3072] and mlp-mid t [4096,4096] (never live together)
    float* qkv = ws;
    float* t   = ws;
    float* ctx = ws + (size_t)4096 * 4096;          // [4096,1024]
    float* r   = ctx + (size_t)4096 * 1024;         // [4096,1024]

    copy_kernel<<<4096, 256, 0, stream>>>(x, h);    // h = x  (4096*1024/4 f4)

    for (int l = 0; l < 16; l++) {
        const float* Wqkv = qkv_w + (size_t)l * 3072 * 1024;
        const float* Bqkv = qkv_b + (size_t)l * 3072;
        const float* Wout = out_w + (size_t)l * 1024 * 1024;
        const float* Bout = out_b + (size_t)l * 1024;
        const float* W1l  = w1 + (size_t)l * 4096 * 1024;
        const float* B1l  = b1 + (size_t)l * 4096;
        const float* W2l  = w2 + (size_t)l * 1024 * 4096;
        const float* B2l  = b2 + (size_t)l * 1024;

        // qkv = h @ Wqkv^T + bias      [4096,3072]
        gemm_kernel<<<dim3(24, 32), 256, 0, stream>>>(h, Wqkv, Bqkv, qkv, 3072, 1024, 0);
        // ctx = causal_attention(qkv)  [4096,1024]
        attn_kernel<<<dim3(16, 64), 256, 0, stream>>>(qkv, ctx);
        // r = ctx @ Wout^T + bias
        gemm_kernel<<<dim3(8, 32), 256, 0, stream>>>(ctx, Wout, Bout, r, 1024, 1024, 0);
        // h = LN1(h + r)
        ln_residual_kernel<<<4096, 256, 0, stream>>>(h, r, ln1w + (size_t)l * 1024, ln1b + (size_t)l * 1024);
        // t = relu(h @ W1^T + b1)      [4096,4096]
        gemm_kernel<<<dim3(32, 32), 256, 0, stream>>>(h, W1l, B1l, t, 4096, 1024, 1);
        // r = t @ W2^T + b2
        gemm_kernel<<<dim3(8, 32), 256, 0, stream>>>(t, W2l, B2l, r, 1024, 4096, 0);
        // h = LN2(h + r)
        ln_residual_kernel<<<4096, 256, 0, stream>>>(h, r, ln2w + (size_t)l * 1024, ln2b + (size_t)l * 1024);
    }
}

// Round 2
// 6702.505 us; speedup vs baseline: 2.3151x; 2.3151x over previous
//
#include <hip/hip_runtime.h>
#include <hip/hip_bf16.h>

typedef float f32x4 __attribute__((ext_vector_type(4)));
typedef __bf16 bf16x8 __attribute__((ext_vector_type(8)));
typedef unsigned short ushort_t;

__device__ __forceinline__ unsigned short f2bf(float f) {
    unsigned int u = __builtin_bit_cast(unsigned int, f);
    u += 0x7fffu + ((u >> 16) & 1u);
    return (unsigned short)(u >> 16);
}

#define GCAST(p) ((const __attribute__((address_space(1))) void*)(p))
#define LCAST(p) ((__attribute__((address_space(3))) void*)(p))

// ---------------------------------------------------------------------------
// Per-layer weight conversion: fp32 -> bf16 into wbf.
// Segments (float4 units): qkv 786432 | out 262144 | w1 1048576 | w2 1048576
// ---------------------------------------------------------------------------
__global__ __launch_bounds__(256) void convert_weights_kernel(
    const float* __restrict__ qw, const float* __restrict__ ow,
    const float* __restrict__ w1, const float* __restrict__ w2,
    unsigned short* __restrict__ dst)
{
    int i = blockIdx.x * 256 + threadIdx.x;     // 0..3145727 (float4 idx)
    const float* src; int off;
    if (i < 786432)       { src = qw; off = i; }
    else if (i < 1048576) { src = ow; off = i - 786432; }
    else if (i < 2097152) { src = w1; off = i - 1048576; }
    else                  { src = w2; off = i - 2097152; }
    float4 v = ((const float4*)src)[off];
    ushort4 u;
    u.x = f2bf(v.x); u.y = f2bf(v.y); u.z = f2bf(v.z); u.w = f2bf(v.w);
    ((ushort4*)dst)[i] = u;
}

// ---------------------------------------------------------------------------
// GEMM: C[M,N] = A[M,K] @ W[N,K]^T + bias[N]; A,W bf16; C fp32 or bf16.
// 256 threads (4 waves), tile 128x128, BK=64, global_load_lds staging.
// ---------------------------------------------------------------------------
__global__ __launch_bounds__(256) void gemm_kernel(
    const unsigned short* __restrict__ A, const unsigned short* __restrict__ W,
    const float* __restrict__ bias, void* __restrict__ Cout,
    int N, int K, int relu, int out_bf16)
{
    __shared__ alignas(16) unsigned short As[128][64];
    __shared__ alignas(16) unsigned short Bs[128][64];

    const int tid  = threadIdx.x;
    const int bn   = blockIdx.x, bm = blockIdx.y;
    const int wave = tid >> 6, lane = tid & 63;
    const int wm   = (wave >> 1) * 64, wn = (wave & 1) * 64;
    const int l15  = lane & 15, quad = lane >> 4;
    const int srow = lane >> 3;            // 0..7
    const int scol = (lane & 7) * 8;       // bf16 element col, 16B chunks

    f32x4 acc[4][4];
#pragma unroll
    for (int i = 0; i < 4; i++)
#pragma unroll
        for (int j = 0; j < 4; j++) acc[i][j] = f32x4{0.f, 0.f, 0.f, 0.f};

    const unsigned short* Abase = A + (size_t)(bm * 128) * K;
    const unsigned short* Wbase = W + (size_t)(bn * 128) * K;

    for (int k0 = 0; k0 < K; k0 += 64) {
        __syncthreads();
#pragma unroll
        for (int i = 0; i < 4; i++) {
            int r0 = (i * 4 + wave) * 8;   // wave-uniform base row
            __builtin_amdgcn_global_load_lds(
                GCAST(&Abase[(size_t)(r0 + srow) * K + k0 + scol]),
                LCAST(&As[r0][0]), 16, 0, 0);
            __builtin_amdgcn_global_load_lds(
                GCAST(&Wbase[(size_t)(r0 + srow) * K + k0 + scol]),
                LCAST(&Bs[r0][0]), 16, 0, 0);
        }
        __syncthreads();

#pragma unroll
        for (int ks = 0; ks < 2; ks++) {
            bf16x8 a[4], b[4];
#pragma unroll
            for (int mt = 0; mt < 4; mt++)
                a[mt] = *reinterpret_cast<const bf16x8*>(&As[wm + mt * 16 + l15][ks * 32 + quad * 8]);
#pragma unroll
            for (int nt = 0; nt < 4; nt++)
                b[nt] = *reinterpret_cast<const bf16x8*>(&Bs[wn + nt * 16 + l15][ks * 32 + quad * 8]);
#pragma unroll
            for (int mt = 0; mt < 4; mt++)
#pragma unroll
                for (int nt = 0; nt < 4; nt++)
                    acc[mt][nt] = __builtin_amdgcn_mfma_f32_16x16x32_bf16(
                        a[mt], b[nt], acc[mt][nt], 0, 0, 0);
        }
    }

    float* Cf = (float*)Cout;
    unsigned short* Cb = (unsigned short*)Cout;
#pragma unroll
    for (int nt = 0; nt < 4; nt++) {
        int gn = bn * 128 + wn + nt * 16 + l15;
        float bv = bias[gn];
#pragma unroll
        for (int mt = 0; mt < 4; mt++) {
            int gm0 = bm * 128 + wm + mt * 16 + quad * 4;
#pragma unroll
            for (int r = 0; r < 4; r++) {
                float v = acc[mt][nt][r] + bv;
                if (relu) v = fmaxf(v, 0.f);
                if (out_bf16) Cb[(size_t)(gm0 + r) * N + gn] = f2bf(v);
                else          Cf[(size_t)(gm0 + r) * N + gn] = v;
            }
        }
    }
}

// ---------------------------------------------------------------------------
// Flash attention, causal. One block = (b, h, 64-row q tile). 256 threads.
// qkv: [B*S, 3072] bf16.  ctx out: [B*S, 1024] bf16.
// ---------------------------------------------------------------------------
__global__ __launch_bounds__(256) void attn_kernel(
    const unsigned short* __restrict__ qkv, unsigned short* __restrict__ ctx)
{
    const int qt = blockIdx.x;          // 0..15
    const int bh = blockIdx.y;          // 0..63
    const int b  = bh >> 4, h = bh & 15;
    const int tid = threadIdx.x, wave = tid >> 6, lane = tid & 63;
    const int l15 = lane & 15, quad = lane >> 4;
    const int srow = lane >> 3, scol = (lane & 7) * 8;
    const float scale = 0.125f;         // 1/sqrt(64)

    __shared__ alignas(16) unsigned short Qs[64][64];
    __shared__ alignas(16) unsigned short Ks[64][64];
    __shared__ alignas(16) unsigned short Vt[64][64];  // [d][k]
    __shared__ alignas(16) unsigned short Ps[64][64];

    const unsigned short* qbase = qkv + (size_t)(b * 1024 + qt * 64) * 3072 + h * 64;
#pragma unroll
    for (int i = 0; i < 2; i++) {
        int r0 = (i * 4 + wave) * 8;
        __builtin_amdgcn_global_load_lds(
            GCAST(&qbase[(size_t)(r0 + srow) * 3072 + scol]),
            LCAST(&Qs[r0][0]), 16, 0, 0);
    }

    f32x4 O[4];
#pragma unroll
    for (int dt = 0; dt < 4; dt++) O[dt] = f32x4{0.f, 0.f, 0.f, 0.f};
    float m_run[4], l_run[4];
#pragma unroll
    for (int r = 0; r < 4; r++) { m_run[r] = -__builtin_inff(); l_run[r] = 0.f; }

    const int q_row_base = qt * 64 + wave * 16;

    for (int j = 0; j <= qt; j++) {
        __syncthreads();
        const unsigned short* kbase = qkv + (size_t)(b * 1024 + j * 64) * 3072 + 1024 + h * 64;
        const unsigned short* vbase = qkv + (size_t)(b * 1024 + j * 64) * 3072 + 2048 + h * 64;
#pragma unroll
        for (int i = 0; i < 2; i++) {
            int r0 = (i * 4 + wave) * 8;
            __builtin_amdgcn_global_load_lds(
                GCAST(&kbase[(size_t)(r0 + srow) * 3072 + scol]),
                LCAST(&Ks[r0][0]), 16, 0, 0);
        }
#pragma unroll
        for (int i = 0; i < 4; i++) {
            int idx = tid + i * 256;
            int row = idx >> 4, c4 = (idx & 15) * 4;
            ushort4 vv = *(const ushort4*)&vbase[(size_t)row * 3072 + c4];
            Vt[c4 + 0][row] = vv.x;
            Vt[c4 + 1][row] = vv.y;
            Vt[c4 + 2][row] = vv.z;
            Vt[c4 + 3][row] = vv.w;
        }
        __syncthreads();

        // S = Q K^T
        f32x4 Sc[4];
#pragma unroll
        for (int nt = 0; nt < 4; nt++) Sc[nt] = f32x4{0.f, 0.f, 0.f, 0.f};
#pragma unroll
        for (int ks = 0; ks < 2; ks++) {
            bf16x8 aq = *reinterpret_cast<const bf16x8*>(&Qs[wave * 16 + l15][ks * 32 + quad * 8]);
#pragma unroll
            for (int nt = 0; nt < 4; nt++) {
                bf16x8 bk = *reinterpret_cast<const bf16x8*>(&Ks[nt * 16 + l15][ks * 32 + quad * 8]);
                Sc[nt] = __builtin_amdgcn_mfma_f32_16x16x32_bf16(aq, bk, Sc[nt], 0, 0, 0);
            }
        }

        float alpha[4];
#pragma unroll
        for (int r = 0; r < 4; r++) {
            int qg = q_row_base + quad * 4 + r;
            float mx = -__builtin_inff();
#pragma unroll
            for (int nt = 0; nt < 4; nt++) {
                int kg = j * 64 + nt * 16 + l15;
                float s = Sc[nt][r] * scale;
                if (kg > qg) s = -__builtin_inff();
                Sc[nt][r] = s;
                mx = fmaxf(mx, s);
            }
#pragma unroll
            for (int off = 1; off < 16; off <<= 1) mx = fmaxf(mx, __shfl_xor(mx, off));
            float mnew = fmaxf(m_run[r], mx);
            alpha[r] = __expf(m_run[r] - mnew);
            m_run[r] = mnew;
        }

#pragma unroll
        for (int r = 0; r < 4; r++) {
            float sum = 0.f;
#pragma unroll
            for (int nt = 0; nt < 4; nt++) {
                float p = __expf(Sc[nt][r] - m_run[r]);
                Sc[nt][r] = p;
                sum += p;
            }
#pragma unroll
            for (int off = 1; off < 16; off <<= 1) sum += __shfl_xor(sum, off);
            l_run[r] = l_run[r] * alpha[r] + sum;
        }

#pragma unroll
        for (int dt = 0; dt < 4; dt++)
#pragma unroll
            for (int r = 0; r < 4; r++) O[dt][r] *= alpha[r];

#pragma unroll
        for (int nt = 0; nt < 4; nt++)
#pragma unroll
            for (int r = 0; r < 4; r++)
                Ps[wave * 16 + quad * 4 + r][nt * 16 + l15] = f2bf(Sc[nt][r]);

#pragma unroll
        for (int ks = 0; ks < 2; ks++) {
            bf16x8 ap = *reinterpret_cast<const bf16x8*>(&Ps[wave * 16 + l15][ks * 32 + quad * 8]);
#pragma unroll
            for (int dt = 0; dt < 4; dt++) {
                bf16x8 bv = *reinterpret_cast<const bf16x8*>(&Vt[dt * 16 + l15][ks * 32 + quad * 8]);
                O[dt] = __builtin_amdgcn_mfma_f32_16x16x32_bf16(ap, bv, O[dt], 0, 0, 0);
            }
        }
    }

    unsigned short* obase = ctx + (size_t)(b * 1024 + qt * 64 + wave * 16) * 1024 + h * 64;
#pragma unroll
    for (int r = 0; r < 4; r++) {
        float inv = 1.f / l_run[r];
#pragma unroll
        for (int dt = 0; dt < 4; dt++)
            obase[(size_t)(quad * 4 + r) * 1024 + dt * 16 + l15] = f2bf(O[dt][r] * inv);
    }
}

// ---------------------------------------------------------------------------
// h = LayerNorm(h + r) * w + b ; writes fp32 h and bf16 hb.
// ---------------------------------------------------------------------------
__global__ __launch_bounds__(256) void ln_residual_kernel(
    float* __restrict__ h, unsigned short* __restrict__ hb,
    const float* __restrict__ r,
    const float* __restrict__ w, const float* __restrict__ b)
{
    const int row = blockIdx.x;
    const int tid = threadIdx.x;
    const int lane = tid & 63, wave = tid >> 6;

    float4 hv = *(float4*)&h[(size_t)row * 1024 + tid * 4];
    float4 rv = *(const float4*)&r[(size_t)row * 1024 + tid * 4];
    float x0 = hv.x + rv.x, x1 = hv.y + rv.y, x2 = hv.z + rv.z, x3 = hv.w + rv.w;

    float s  = x0 + x1 + x2 + x3;
    float s2 = x0 * x0 + x1 * x1 + x2 * x2 + x3 * x3;
#pragma unroll
    for (int off = 32; off >= 1; off >>= 1) {
        s  += __shfl_xor(s, off);
        s2 += __shfl_xor(s2, off);
    }
    __shared__ float ls[4], ls2[4];
    if (lane == 0) { ls[wave] = s; ls2[wave] = s2; }
    __syncthreads();
    s  = ls[0] + ls[1] + ls[2] + ls[3];
    s2 = ls2[0] + ls2[1] + ls2[2] + ls2[3];

    const float inv_n = 1.f / 1024.f;
    float mean = s * inv_n;
    float var  = s2 * inv_n - mean * mean;
    float rstd = rsqrtf(var + 1e-5f);

    float4 wv = *(const float4*)&w[tid * 4];
    float4 bv = *(const float4*)&b[tid * 4];
    float4 out;
    out.x = (x0 - mean) * rstd * wv.x + bv.x;
    out.y = (x1 - mean) * rstd * wv.y + bv.y;
    out.z = (x2 - mean) * rstd * wv.z + bv.z;
    out.w = (x3 - mean) * rstd * wv.w + bv.w;
    *(float4*)&h[(size_t)row * 1024 + tid * 4] = out;
    ushort4 ub;
    ub.x = f2bf(out.x); ub.y = f2bf(out.y); ub.z = f2bf(out.z); ub.w = f2bf(out.w);
    *(ushort4*)&hb[(size_t)row * 1024 + tid * 4] = ub;
}

__global__ __launch_bounds__(256) void copy_convert_kernel(
    const float* __restrict__ in, float* __restrict__ h, unsigned short* __restrict__ hb)
{
    int i = blockIdx.x * 256 + threadIdx.x;
    float4 v = ((const float4*)in)[i];
    ((float4*)h)[i] = v;
    ushort4 u;
    u.x = f2bf(v.x); u.y = f2bf(v.y); u.z = f2bf(v.z); u.w = f2bf(v.w);
    ((ushort4*)hb)[i] = u;
}

// ---------------------------------------------------------------------------
extern "C" void kernel_launch(void* const* d_in, const int* in_sizes, int n_in,
                              void* d_out, int out_size, void* d_ws, size_t ws_size,
                              hipStream_t stream)
{
    const float* x     = (const float*)d_in[0];
    const float* qkv_w = (const float*)d_in[1];
    const float* qkv_b = (const float*)d_in[2];
    const float* out_w = (const float*)d_in[3];
    const float* out_b = (const float*)d_in[4];
    const float* w1    = (const float*)d_in[5];
    const float* b1    = (const float*)d_in[6];
    const float* w2    = (const float*)d_in[7];
    const float* b2    = (const float*)d_in[8];
    const float* ln1w  = (const float*)d_in[9];
    const float* ln1b  = (const float*)d_in[10];
    const float* ln2w  = (const float*)d_in[11];
    const float* ln2b  = (const float*)d_in[12];

    float* h = (float*)d_out;                       // fp32 residual stream [4096,1024]
    char* ws = (char*)d_ws;
    // shared region: qkv bf16 [4096,3072] (25.2MB) aliased with t bf16 [4096,4096] (33.6MB)
    unsigned short* qkvb = (unsigned short*)ws;
    unsigned short* tb   = (unsigned short*)ws;
    unsigned short* ctxb = (unsigned short*)(ws + 33554432);          // [4096,1024] bf16
    unsigned short* hb   = (unsigned short*)(ws + 33554432 + 8388608); // [4096,1024] bf16
    unsigned short* wbf  = (unsigned short*)(ws + 50331648);          // 12.58M bf16 weights
    float*          r    = (float*)(ws + 75497472);                   // [4096,1024] fp32

    unsigned short* wb_qkv = wbf;
    unsigned short* wb_out = wbf + 3145728;
    unsigned short* wb_w1  = wbf + 4194304;
    unsigned short* wb_w2  = wbf + 8388608;

    copy_convert_kernel<<<4096, 256, 0, stream>>>(x, h, hb);

    for (int l = 0; l < 16; l++) {
        convert_weights_kernel<<<12288, 256, 0, stream>>>(
            qkv_w + (size_t)l * 3145728, out_w + (size_t)l * 1048576,
            w1 + (size_t)l * 4194304, w2 + (size_t)l * 4194304, wbf);

        // qkv = hb @ Wqkv^T + b           [4096,3072] bf16
        gemm_kernel<<<dim3(24, 32), 256, 0, stream>>>(
            hb, wb_qkv, qkv_b + (size_t)l * 3072, qkvb, 3072, 1024, 0, 1);
        // ctx = causal_attention(qkv)     [4096,1024] bf16
        attn_kernel<<<dim3(16, 64), 256, 0, stream>>>(qkvb, ctxb);
        // r = ctx @ Wout^T + b            fp32
        gemm_kernel<<<dim3(8, 32), 256, 0, stream>>>(
            ctxb, wb_out, out_b + (size_t)l * 1024, r, 1024, 1024, 0, 0);
        // h = LN1(h + r); hb = bf16(h)
        ln_residual_kernel<<<4096, 256, 0, stream>>>(
            h, hb, r, ln1w + (size_t)l * 1024, ln1b + (size_t)l * 1024);
        // t = relu(hb @ W1^T + b1)        [4096,4096] bf16
        gemm_kernel<<<dim3(32, 32), 256, 0, stream>>>(
            hb, wb_w1, b1 + (size_t)l * 4096, tb, 4096, 1024, 1, 1);
        // r = t @ W2^T + b2               fp32
        gemm_kernel<<<dim3(8, 32), 256, 0, stream>>>(
            tb, wb_w2, b2 + (size_t)l * 1024, r, 1024, 4096, 0, 0);
        // h = LN2(h + r); hb = bf16(h)
        ln_residual_kernel<<<4096, 256, 0, stream>>>(
            h, hb, r, ln2w + (size_t)l * 1024, ln2b + (size_t)l * 1024);
    }
}